// Round 2
// baseline (130.248 us; speedup 1.0000x reference)
//
#include <hip/hip_runtime.h>

#define EPS 1e-6f

__device__ __forceinline__ float elu1(float x) {
    // elu(x) + 1  ==  x > 0 ? x + 1 : exp(x)
    return x > 0.f ? x + 1.f : __expf(x);
}

// ---------------------------------------------------------------------------
// Phase 1: partial KV outer products, NO atomics.
// Grid (64 nh, CH chunks), 128 threads (2 waves). Each block stages
// tiles of 64 s-rows (K' = elu+mask, V raw) in LDS and accumulates a full
// 64x64 partial: thread tile (8m x 4d), m0=(t>>4)*8, d0=(t&15)*4.
// Partial dump: pkv[c][nh][k=i*4+j][t]  (each store instr = 256B contiguous).
// Partial ksum: pks[c][nh][d].
// ---------------------------------------------------------------------------
__global__ __launch_bounds__(128) void kv_partial_kernel(
    const float* __restrict__ keys, const float* __restrict__ values,
    const float* __restrict__ mask, float* __restrict__ pkv,
    float* __restrict__ pks, int tiles)
{
    __shared__ float Ks[64][64];   // stride 64: conflict-free at 8-lane phases
    __shared__ float Vs[64][64];

    const int nh = blockIdx.x;
    const int n = nh >> 4, h = nh & 15;
    const int t = threadIdx.x;
    const int seg = t & 15;        // staging col group == d-group
    const int rbase = t >> 4;      // staging row base (0..7)
    const int d0 = seg * 4;
    const int m0 = rbase * 8;

    const int chunk = blockIdx.y;
    const int s00 = chunk * (tiles * 64);

    const float* kbase = keys   + ((size_t)(n * 4096 + s00) * 16 + h) * 64 + d0;
    const float* vbase = values + ((size_t)(n * 4096 + s00) * 16 + h) * 64 + d0;
    const float* mbase = mask + n * 4096 + s00;

    float4 kr[8], vr[8];
    float mr[8];
    float acc[8][4];
    #pragma unroll
    for (int i = 0; i < 8; ++i)
        #pragma unroll
        for (int j = 0; j < 4; ++j) acc[i][j] = 0.f;
    float4 ks4 = make_float4(0.f, 0.f, 0.f, 0.f);

    // prefetch tile 0 (16 float4 + 8 mask scalars)
    #pragma unroll
    for (int k = 0; k < 8; ++k) {
        const int row = rbase + 8 * k;
        kr[k] = *(const float4*)(kbase + (size_t)row * 1024);
        vr[k] = *(const float4*)(vbase + (size_t)row * 1024);
        mr[k] = mbase[row];
    }

    for (int tile = 0; tile < tiles; ++tile) {
        __syncthreads();           // previous compute done -> LDS reusable
        // transform K (elu+mask) + accumulate ksum + stage both tiles
        #pragma unroll
        for (int k = 0; k < 8; ++k) {
            const int row = rbase + 8 * k;
            float4 kk = kr[k];
            const float msk = mr[k];
            kk.x = elu1(kk.x) * msk; kk.y = elu1(kk.y) * msk;
            kk.z = elu1(kk.z) * msk; kk.w = elu1(kk.w) * msk;
            ks4.x += kk.x; ks4.y += kk.y; ks4.z += kk.z; ks4.w += kk.w;
            *(float4*)&Ks[row][d0] = kk;
            *(float4*)&Vs[row][d0] = vr[k];
        }
        __syncthreads();
        // issue next tile's global loads; they fly under the compute loop
        if (tile + 1 < tiles) {
            const size_t off = (size_t)(tile + 1) * 64 * 1024;
            #pragma unroll
            for (int k = 0; k < 8; ++k) {
                const int row = rbase + 8 * k;
                kr[k] = *(const float4*)(kbase + off + (size_t)row * 1024);
                vr[k] = *(const float4*)(vbase + off + (size_t)row * 1024);
                mr[k] = mbase[(tile + 1) * 64 + row];
            }
        }
        // outer-product accumulate: per s, 3x ds_read_b128 -> 32 FMA
        #pragma unroll 4
        for (int s = 0; s < 64; ++s) {
            const float4 k4 = *(const float4*)&Ks[s][d0];
            const float4 va = *(const float4*)&Vs[s][m0];
            const float4 vb = *(const float4*)&Vs[s][m0 + 4];
            const float kk[4] = {k4.x, k4.y, k4.z, k4.w};
            const float vv[8] = {va.x, va.y, va.z, va.w, vb.x, vb.y, vb.z, vb.w};
            #pragma unroll
            for (int i = 0; i < 8; ++i)
                #pragma unroll
                for (int j = 0; j < 4; ++j)
                    acc[i][j] = fmaf(vv[i], kk[j], acc[i][j]);
        }
    }

    // ksum partial: reduce 8 rbase-threads per seg via LDS (reuse Ks)
    __syncthreads();
    float* kred = &Ks[0][0];
    *(float4*)&kred[rbase * 64 + d0] = ks4;
    __syncthreads();
    if (t < 16) {
        float4 s4 = make_float4(0.f, 0.f, 0.f, 0.f);
        #pragma unroll
        for (int r = 0; r < 8; ++r) {
            const float4 v = *(const float4*)&kred[r * 64 + t * 4];
            s4.x += v.x; s4.y += v.y; s4.z += v.z; s4.w += v.w;
        }
        *(float4*)(pks + ((size_t)chunk * 64 + nh) * 64 + t * 4) = s4;
    }

    // dump partial KV: pkv[chunk][nh][i*4+j][t] -- fully coalesced stores
    float* pb = pkv + ((size_t)chunk * 64 + nh) * 4096;
    #pragma unroll
    for (int i = 0; i < 8; ++i)
        #pragma unroll
        for (int j = 0; j < 4; ++j)
            pb[(i * 4 + j) * 128 + t] = acc[i][j];
}

// ---------------------------------------------------------------------------
// Reduce: kvt[nh][d][m] = sum_c pkv[c][nh][k][t] (unscrambled);
//         ksum[nh][d]   = sum_c pks[c][nh][d].
// Grid (64 nh, 4), 256 threads; one float4 slab slot per thread.
// ---------------------------------------------------------------------------
__global__ __launch_bounds__(256) void kv_reduce_kernel(
    const float* __restrict__ pkv, const float* __restrict__ pks,
    float* __restrict__ kvt, float* __restrict__ ksum, int CH)
{
    const int nh = blockIdx.x;
    const int f = blockIdx.y * 256 + threadIdx.x;  // float4 slot 0..1023
    float4 s4 = make_float4(0.f, 0.f, 0.f, 0.f);
    for (int c = 0; c < CH; ++c) {
        const float4 v = *(const float4*)(pkv + ((size_t)c * 64 + nh) * 4096 + f * 4);
        s4.x += v.x; s4.y += v.y; s4.z += v.z; s4.w += v.w;
    }
    const float vals[4] = {s4.x, s4.y, s4.z, s4.w};
    #pragma unroll
    for (int u = 0; u < 4; ++u) {
        const int flat = f * 4 + u;                // k*128 + t
        const int k = flat >> 7, ts = flat & 127;
        const int m = ((ts >> 4) << 3) + (k >> 2);
        const int d = ((ts & 15) << 2) + (k & 3);
        kvt[(size_t)nh * 4096 + d * 64 + m] = vals[u];
    }
    if (blockIdx.y == 0 && threadIdx.x < 64) {
        float s = 0.f;
        for (int c = 0; c < CH; ++c)
            s += pks[((size_t)c * 64 + nh) * 64 + threadIdx.x];
        ksum[nh * 64 + threadIdx.x] = s;
    }
}

// ---------------------------------------------------------------------------
// Phase 2: out[n,l,h,m] = z_l * sum_d Q'[l,d] * KVT[d,m],
//          z_l = 1/(sum_d Q'[l,d]*Ksum[d] + EPS)
// ---------------------------------------------------------------------------
__global__ __launch_bounds__(256) void out_kernel(
    const float* __restrict__ queries, const float* __restrict__ kvt,
    const float* __restrict__ ksum, float* __restrict__ out)
{
    __shared__ float QsT[64][132];  // [d][l]
    __shared__ float KVs[64][68];   // [d][m]
    __shared__ float Ksm[64];
    __shared__ float Zs[128];

    const int nh = blockIdx.x;
    const int n = nh >> 4, h = nh & 15;
    const int t = threadIdx.x;
    const int l0 = blockIdx.y * 128;

    #pragma unroll
    for (int k = 0; k < 4; ++k) {
        const int idx = t + k * 256;
        const int dd = idx >> 4, seg = idx & 15;
        const float4 v = *(const float4*)(kvt + (size_t)nh * 4096 + idx * 4);
        *(float4*)&KVs[dd][seg * 4] = v;
    }
    if (t < 64) Ksm[t] = ksum[nh * 64 + t];

    #pragma unroll
    for (int k = 0; k < 8; ++k) {
        const int idx = t + k * 256;
        const int row = idx >> 4, seg = idx & 15;
        const size_t g = ((size_t)(n * 4096 + l0 + row) * 16 + h) * 64 + seg * 4;
        float4 q4 = *(const float4*)(queries + g);
        q4.x = elu1(q4.x);
        q4.y = elu1(q4.y);
        q4.z = elu1(q4.z);
        q4.w = elu1(q4.w);
        QsT[seg * 4 + 0][row] = q4.x;
        QsT[seg * 4 + 1][row] = q4.y;
        QsT[seg * 4 + 2][row] = q4.z;
        QsT[seg * 4 + 3][row] = q4.w;
    }
    __syncthreads();

    if (t < 128) {
        float a = 0.f;
        #pragma unroll 8
        for (int d = 0; d < 64; ++d) a = fmaf(QsT[d][t], Ksm[d], a);
        Zs[t] = 1.f / (a + EPS);
    }
    __syncthreads();

    const int mg = t & 7, lg = t >> 3;
    const int m0 = mg * 8, lt = lg * 4;
    float acc[4][8];
    #pragma unroll
    for (int i = 0; i < 4; ++i)
        #pragma unroll
        for (int j = 0; j < 8; ++j) acc[i][j] = 0.f;

    #pragma unroll 4
    for (int d = 0; d < 64; ++d) {
        const float4 q4 = *(const float4*)&QsT[d][lt];
        const float4 a4 = *(const float4*)&KVs[d][m0];
        const float4 b4 = *(const float4*)&KVs[d][m0 + 4];
        const float qq[4] = {q4.x, q4.y, q4.z, q4.w};
        const float mm[8] = {a4.x, a4.y, a4.z, a4.w, b4.x, b4.y, b4.z, b4.w};
        #pragma unroll
        for (int i = 0; i < 4; ++i)
            #pragma unroll
            for (int j = 0; j < 8; ++j)
                acc[i][j] = fmaf(qq[i], mm[j], acc[i][j]);
    }

    #pragma unroll
    for (int i = 0; i < 4; ++i) {
        const float z = Zs[lt + i];
        const size_t g = ((size_t)(n * 4096 + l0 + lt + i) * 16 + h) * 64 + m0;
        float4 o;
        o.x = acc[i][0] * z; o.y = acc[i][1] * z;
        o.z = acc[i][2] * z; o.w = acc[i][3] * z;
        *(float4*)(out + g) = o;
        o.x = acc[i][4] * z; o.y = acc[i][5] * z;
        o.z = acc[i][6] * z; o.w = acc[i][7] * z;
        *(float4*)(out + g + 4) = o;
    }
}

extern "C" void kernel_launch(void* const* d_in, const int* in_sizes, int n_in,
                              void* d_out, int out_size, void* d_ws, size_t ws_size,
                              hipStream_t stream) {
    const float* queries = (const float*)d_in[0];
    const float* keys    = (const float*)d_in[1];
    const float* values  = (const float*)d_in[2];
    const float* mask    = (const float*)d_in[3];
    float* out = (float*)d_out;

    // pick chunk count that fits the workspace (deterministic: ws_size fixed)
    int CH = 16;
    while (CH > 1) {
        size_t need = ((size_t)CH * 64 * 4096 + (size_t)CH * 64 * 64 +
                       (size_t)64 * 4096 + 64 * 64) * sizeof(float);
        if (need <= ws_size) break;
        CH >>= 1;
    }
    const int tiles = 64 / CH;   // 64-row tiles per block

    float* pkv  = (float*)d_ws;                         // [CH][64][4096]
    float* pks  = pkv + (size_t)CH * 64 * 4096;         // [CH][64][64]
    float* kvt  = pks + (size_t)CH * 64 * 64;           // [64][64][64] (d,m)
    float* ksum = kvt + (size_t)64 * 4096;              // [64][64]

    kv_partial_kernel<<<dim3(64, CH), 128, 0, stream>>>(keys, values, mask,
                                                        pkv, pks, tiles);
    kv_reduce_kernel<<<dim3(64, 4), 256, 0, stream>>>(pkv, pks, kvt, ksum, CH);
    out_kernel<<<dim3(64, 32), 256, 0, stream>>>(queries, kvt, ksum, out);
}